// Round 5
// baseline (443.389 us; speedup 1.0000x reference)
//
#include <hip/hip_runtime.h>
#include <math.h>
#include <utility>

#define K_COMP 64
#define D 32
#define NTRIL (D*(D-1)/2)          // 496
#define ICF_COLS (D + NTRIL)       // 528
#define BLK 256
#define PTS_PER_BLK 64
#define KSPLIT 4                   // k-blocks per point-block
#define K_PER_WAVE 4               // 4 waves * 4 k = 16 k per block
#define CHUNK 64                   // tril values staged per register chunk

// compile-time (row, col) from packed column-major strict-lower-tri index
constexpr int tril_c_of(int p) {
  int c = 0, off = 0;
  while (off + (D - 1 - c) <= p) { off += D - 1 - c; ++c; }
  return c;
}
constexpr int tril_off_of_col(int c) {
  int off = 0;
  for (int j = 0; j < c; ++j) off += D - 1 - j;
  return off;
}
constexpr int tril_r_of(int p) {
  int c = tril_c_of(p);
  return c + 1 + (p - tril_off_of_col(c));
}

// ---- chunked tril matvec: pure float4 load block, then pure FMA block ----
template<int P0, int NV>
struct TrilChunk {
  template<int I>
  static __device__ __forceinline__ void one(const float4 (&buf)[NV/4],
                                             const float (&xr)[D], float (&lx)[D]) {
    constexpr int P = P0 + I;
    constexpr int r = tril_r_of(P);
    constexpr int c = tril_c_of(P);
    constexpr int q = I / 4, mm = I % 4;
    float l = (mm == 0) ? buf[q].x : (mm == 1) ? buf[q].y : (mm == 2) ? buf[q].z : buf[q].w;
    lx[r] = fmaf(l, xr[c], lx[r]);
  }
  template<size_t... Is>
  static __device__ __forceinline__ void fmas(const float4 (&buf)[NV/4],
                                              const float (&xr)[D], float (&lx)[D],
                                              std::index_sequence<Is...>) {
    (one<(int)Is>(buf, xr, lx), ...);
  }
  static __device__ __forceinline__ void run(const float4* __restrict__ lk4,
                                             const float (&xr)[D], float (&lx)[D]) {
    float4 buf[NV/4];
#pragma unroll
    for (int j = 0; j < NV/4; ++j) buf[j] = lk4[P0/4 + j];   // imm-offset dwordx4
    fmas(buf, xr, lx, std::make_index_sequence<NV>{});
  }
};

template<int P0>
__device__ __forceinline__ void tril_chunks(const float4* __restrict__ lk4,
                                            const float (&xr)[D], float (&lx)[D]) {
  if constexpr (P0 < NTRIL) {
    constexpr int NV = (NTRIL - P0 >= CHUNK) ? CHUNK : (NTRIL - P0);
    TrilChunk<P0, NV>::run(lk4, xr, lx);
    tril_chunks<P0 + NV>(lk4, xr, lx);
  }
}

// ---- prep helpers (1 tiny block, keep simple fold form) ----
template<int P>
__device__ __forceinline__ void tril_step_prep(const float* __restrict__ lk,
                                               const float (&mr)[D], float (&b)[D],
                                               float& lsq) {
  constexpr int r = tril_r_of(P);
  constexpr int c = tril_c_of(P);
  float l = lk[P];
  b[r] = fmaf(l, mr[c], b[r]);
  lsq = fmaf(l, l, lsq);
}
template<size_t... Ps>
__device__ __forceinline__ void tril_matvec_prep(const float* __restrict__ lk,
                                                 const float (&mr)[D], float (&b)[D],
                                                 float& lsq,
                                                 std::index_sequence<Ps...>) {
  (tril_step_prep<(int)Ps>(lk, mr, b, lsq), ...);
}

// ws layout (floats):
// [0,    2048) Qd[k][i]
// [2048, 4096) b[k][i] = M[k] @ means[k]
// [4096, 4160) ak[k] = alphas[k] + sum_qs[k]
// [4160, 4224) wk[k] = per-k wishart term
// [4224, ...)  ms[kb][n] float2 partials, then merge partials

__global__ __launch_bounds__(K_COMP) void gmm_prep(
    const float* __restrict__ alphas, const float* __restrict__ means,
    const float* __restrict__ icf, const float* __restrict__ wg,
    const float* __restrict__ wm, float* __restrict__ ws)
{
  int k = threadIdx.x;
  const float* ick = icf + k * ICF_COLS;
  const float* mk  = means + k * D;

  float qd[D], b[D], mr[D];
  float sumq = 0.f, qsq = 0.f;
#pragma unroll
  for (int i = 0; i < D; ++i) {
    float v = ick[i];
    sumq += v;
    float q = __expf(v);
    qd[i] = q;
    qsq = fmaf(q, q, qsq);
  }
#pragma unroll
  for (int i = 0; i < D; ++i) { mr[i] = mk[i]; b[i] = qd[i] * mr[i]; }

  float lsq = 0.f;
  tril_matvec_prep(ick + D, mr, b, lsq, std::make_index_sequence<NTRIL>{});

  float* wqd = ws;
  float* wb  = ws + K_COMP * D;
  float* wak = ws + 2 * K_COMP * D;
  float* wwk = wak + K_COMP;
#pragma unroll
  for (int i = 0; i < D; ++i) { wqd[k*D + i] = qd[i]; wb[k*D + i] = b[i]; }
  wak[k] = alphas[k] + sumq;
  float g = wg[0], m = wm[0];
  wwk[k] = 0.5f * g * g * (qsq + lsq) - m * sumq;
}

__global__ __launch_bounds__(BLK, 4) void gmm_main(
    const float* __restrict__ x, const float* __restrict__ icf,
    const float* __restrict__ ws, int N, int Npad, float2* __restrict__ ms)
{
  const float* wqd = ws;
  const float* wb  = ws + K_COMP * D;
  const float* wak = ws + 2 * K_COMP * D;

  int tid  = threadIdx.x;
  int lane = tid & 63;
  int wv   = __builtin_amdgcn_readfirstlane(tid >> 6);  // wave-uniform
  int kb   = blockIdx.x & (KSPLIT - 1);
  int pblk = blockIdx.x >> 2;
  int n = pblk * PTS_PER_BLK + lane;
  int nn = (n < N) ? n : (N - 1);

  float xr[D];
  const float4* xp = reinterpret_cast<const float4*>(x + (size_t)nn * D);
#pragma unroll
  for (int i = 0; i < D / 4; ++i) {
    float4 v = xp[i];
    xr[4*i+0] = v.x; xr[4*i+1] = v.y; xr[4*i+2] = v.z; xr[4*i+3] = v.w;
  }

  float m = -INFINITY, s = 0.f;
  int k0 = kb * (KSPLIT * K_PER_WAVE) + wv * K_PER_WAVE;
#pragma unroll 1
  for (int k = k0; k < k0 + K_PER_WAVE; ++k) {
    const float4* qk4 = reinterpret_cast<const float4*>(wqd + k * D);
    const float4* bk4 = reinterpret_cast<const float4*>(wb  + k * D);
    const float4* lk4 = reinterpret_cast<const float4*>(icf + (size_t)k * ICF_COLS + D);

    // staged float4 loads for diag & bias, then FMA block
    float4 qb[D/4], bb[D/4];
#pragma unroll
    for (int j = 0; j < D/4; ++j) { qb[j] = qk4[j]; bb[j] = bk4[j]; }

    float lx[D];
#pragma unroll
    for (int j = 0; j < D/4; ++j) {
      lx[4*j+0] = fmaf(qb[j].x, xr[4*j+0], -bb[j].x);
      lx[4*j+1] = fmaf(qb[j].y, xr[4*j+1], -bb[j].y);
      lx[4*j+2] = fmaf(qb[j].z, xr[4*j+2], -bb[j].z);
      lx[4*j+3] = fmaf(qb[j].w, xr[4*j+3], -bb[j].w);
    }

    // 496 FMAs in 8 chunks: 16 dwordx4 loads then 64 FMAs per chunk
    tril_chunks<0>(lk4, xr, lx);

    float s0 = 0.f, s1 = 0.f, s2 = 0.f, s3 = 0.f;
#pragma unroll
    for (int i = 0; i < D; i += 4) {
      s0 = fmaf(lx[i+0], lx[i+0], s0);
      s1 = fmaf(lx[i+1], lx[i+1], s1);
      s2 = fmaf(lx[i+2], lx[i+2], s2);
      s3 = fmaf(lx[i+3], lx[i+3], s3);
    }
    float sq = (s0 + s1) + (s2 + s3);
    float inner = wak[k] - 0.5f * sq;

    float mn = fmaxf(m, inner);
    s = s * __expf(m - mn) + __expf(inner - mn);
    m = mn;
  }

  // merge the 4 per-wave (m,s) partials for each point via LDS
  __shared__ float lm[4][PTS_PER_BLK];
  __shared__ float ls[4][PTS_PER_BLK];
  lm[wv][lane] = m;
  ls[wv][lane] = s;
  __syncthreads();

  if (tid < PTS_PER_BLK) {
    float mm = lm[0][tid];
#pragma unroll
    for (int w = 1; w < 4; ++w) mm = fmaxf(mm, lm[w][tid]);
    float ss = 0.f;
#pragma unroll
    for (int w = 0; w < 4; ++w) ss += ls[w][tid] * __expf(lm[w][tid] - mm);
    ms[(size_t)kb * Npad + pblk * PTS_PER_BLK + tid] = make_float2(mm, ss);
  }
}

__global__ __launch_bounds__(256) void gmm_merge(
    const float2* __restrict__ ms, int N, int Npad, float* __restrict__ partials)
{
  int tid = threadIdx.x;
  int idx = blockIdx.x * 256 + tid;
  int ii = (idx < N) ? idx : 0;

  float m[KSPLIT], s[KSPLIT];
#pragma unroll
  for (int kb = 0; kb < KSPLIT; ++kb) {
    float2 v = ms[(size_t)kb * Npad + ii];
    m[kb] = v.x; s[kb] = v.y;
  }
  float mm = m[0];
#pragma unroll
  for (int kb = 1; kb < KSPLIT; ++kb) mm = fmaxf(mm, m[kb]);
  float ss = 0.f;
#pragma unroll
  for (int kb = 0; kb < KSPLIT; ++kb) ss += s[kb] * __expf(m[kb] - mm);
  float lse = (idx < N) ? (mm + __logf(ss)) : 0.f;

  __shared__ float red[256];
  red[tid] = lse;
  __syncthreads();
#pragma unroll
  for (int st = 128; st > 0; st >>= 1) {
    if (tid < st) red[tid] += red[tid + st];
    __syncthreads();
  }
  if (tid == 0) partials[blockIdx.x] = red[0];
}

__global__ __launch_bounds__(256) void gmm_final(
    const float* __restrict__ wwk, const float* __restrict__ partials, int nblocks,
    const float* __restrict__ alphas, const float* __restrict__ wg,
    const float* __restrict__ wm, int N, float* __restrict__ out)
{
  int tid = threadIdx.x;
  __shared__ double sacc[256];
  double acc = 0.0;
  for (int i = tid; i < nblocks; i += 256) acc += (double)partials[i];
  sacc[tid] = acc;
  __syncthreads();
  for (int st = 128; st > 0; st >>= 1) {
    if (tid < st) sacc[tid] += sacc[tid + st];
    __syncthreads();
  }

  if (tid == 0) {
    double slse = sacc[0];

    float amax = alphas[0];
    for (int k = 1; k < K_COMP; ++k) amax = fmaxf(amax, alphas[k]);
    double sa = 0.0;
    for (int k = 0; k < K_COMP; ++k) sa += exp((double)(alphas[k] - amax));
    double lse_a = (double)amax + log(sa);

    double ow = 0.0;
    for (int k = 0; k < K_COMP; ++k) ow += (double)wwk[k];

    double g = (double)wg[0], wmv = (double)wm[0];
    double nw = (double)D + wmv + 1.0;
    double C = nw * (double)D * log(g / sqrt(2.0));
    double mg = (D * (D - 1) / 4.0) * log(M_PI);
    for (int j = 1; j <= D; ++j) mg += lgamma(0.5 * nw + (1.0 - j) * 0.5);

    double CONST = -(double)N * D * 0.5 * log(2.0 * M_PI);
    double prior = ow - (double)K_COMP * (C - mg);

    out[0] = (float)(CONST + slse - (double)N * lse_a + prior);
  }
}

extern "C" void kernel_launch(void* const* d_in, const int* in_sizes, int n_in,
                              void* d_out, int out_size, void* d_ws, size_t ws_size,
                              hipStream_t stream)
{
  const float* alphas = (const float*)d_in[0];
  const float* means  = (const float*)d_in[1];
  const float* icf    = (const float*)d_in[2];
  const float* x      = (const float*)d_in[3];
  const float* wg     = (const float*)d_in[4];
  const float* wm     = (const float*)d_in[5];
  float* out = (float*)d_out;
  float* ws  = (float*)d_ws;

  int N = in_sizes[3] / D;
  int npblk = (N + PTS_PER_BLK - 1) / PTS_PER_BLK;   // 782
  int Npad  = npblk * PTS_PER_BLK;                    // 50048
  int nmerge = (N + 255) / 256;                       // 196

  float*  wwk      = ws + 2 * K_COMP * D + K_COMP;
  float2* ms       = (float2*)(ws + 2 * K_COMP * D + 2 * K_COMP);
  float*  partials = (float*)(ms + (size_t)KSPLIT * Npad);

  gmm_prep<<<1, K_COMP, 0, stream>>>(alphas, means, icf, wg, wm, ws);
  gmm_main<<<npblk * KSPLIT, BLK, 0, stream>>>(x, icf, ws, N, Npad, ms);
  gmm_merge<<<nmerge, 256, 0, stream>>>(ms, N, Npad, partials);
  gmm_final<<<1, 256, 0, stream>>>(wwk, partials, nmerge, alphas, wg, wm, N, out);
}

// Round 6
// 66.984 us; speedup vs baseline: 6.6193x; 6.6193x over previous
//
#include <hip/hip_runtime.h>
#include <math.h>
#include <utility>

#define K_COMP 64
#define D 32
#define NTRIL 496
#define ICF_COLS 528
#define NPAIR 528            // i<=j pairs
#define NF 561               // 1 + 32 + 528
#define NCHUNK 18            // 576 = 18*32 padded features
#define PTS_PER_BLK 32
#define ROWB 1168            // LDS feature-row stride in bytes (576*2 + 16)

typedef __attribute__((ext_vector_type(8))) short v8s;
typedef __attribute__((ext_vector_type(4))) float v4f;

__device__ __forceinline__ unsigned short f2bf(float f) {
  unsigned int u = __float_as_uint(f);
  unsigned int r = (u + 0x7FFFu + ((u >> 16) & 1u)) >> 16;
  return (unsigned short)r;
}
__device__ __forceinline__ float bf2f(unsigned short h) {
  return __uint_as_float((unsigned int)h << 16);
}
__device__ __forceinline__ v8s asv8(int4 v) {
  union { int4 i; v8s s; } u; u.i = v; return u.s;
}

// pair enumeration t -> (i,j), i<=j, i ascending, j from i..31
constexpr int pr_i(int t) { int i = 0; while (t >= D - i) { t -= D - i; ++i; } return i; }
constexpr int pr_j(int t) { int i = 0; while (t >= D - i) { t -= D - i; ++i; } return i + t; }

template<int F> __device__ __forceinline__ float feat(const float (&xr)[D]) {
  if constexpr (F == 0) return 1.0f;
  else if constexpr (F <= 32) return xr[F - 1];
  else if constexpr (F <= 560) {
    constexpr int t = F - 33, i = pr_i(t), j = pr_j(t);
    return xr[i] * xr[j];
  } else return 0.0f;
}

template<int F0> __device__ __forceinline__ void write4(const float (&xr)[D], char* row) {
  unsigned int d0 = (unsigned int)f2bf(feat<F0+0>(xr)) | ((unsigned int)f2bf(feat<F0+1>(xr)) << 16);
  unsigned int d1 = (unsigned int)f2bf(feat<F0+2>(xr)) | ((unsigned int)f2bf(feat<F0+3>(xr)) << 16);
  *reinterpret_cast<uint2*>(row + (size_t)F0 * 2) = make_uint2(d0, d1);
}
template<int BASE, size_t... Qs> __device__ __forceinline__
void gen72(const float (&xr)[D], char* row, std::index_sequence<Qs...>) {
  (write4<BASE + 4 * (int)Qs>(xr, row), ...);
}

// ------------------- prep: one block per component k -------------------
__global__ __launch_bounds__(64) void gmm_prep(
    const float* __restrict__ alphas, const float* __restrict__ means,
    const float* __restrict__ icf, const float* __restrict__ wg,
    const float* __restrict__ wm,
    uint4* __restrict__ Whi, uint4* __restrict__ Wlo, float* __restrict__ wwk)
{
  int k = blockIdx.x;
  int l = threadIdx.x;
  __shared__ float M[D][D + 1];
  __shared__ float mu[D], b[D], v[D];
  __shared__ float At[NPAIR];
  __shared__ float red[64];
  __shared__ float eS;

  const float* ick = icf + (size_t)k * ICF_COLS;

  if (l < D) {
    mu[l] = means[k * D + l];
    float q = __expf(ick[l]);
    for (int c = 0; c < D; ++c) {
      float val;
      if (c < l) { int off = c * 31 - c * (c - 1) / 2; val = ick[D + off + (l - c - 1)]; }
      else if (c == l) val = q;
      else val = 0.0f;
      M[l][c] = val;
    }
  }
  __syncthreads();
  if (l < D) {
    float acc = 0.f;
    for (int c = 0; c < D; ++c) acc = fmaf(M[l][c], mu[c], acc);
    b[l] = acc;
  }
  __syncthreads();
  if (l < D) {
    float acc = 0.f;
    for (int r = 0; r < D; ++r) acc = fmaf(M[r][l], b[r], acc);
    v[l] = acc;
  }
  // A[i<=j] = sum_r M[r,i]*M[r,j]; store with GEMM sign convention
  for (int t = l; t < NPAIR; t += 64) {
    int tt = t, i = 0;
    while (tt >= D - i) { tt -= D - i; ++i; }
    int j = i + tt;
    float acc = 0.f;
    for (int r = 0; r < D; ++r) acc = fmaf(M[r][i], M[r][j], acc);
    At[t] = (i == j) ? -0.5f * acc : -acc;
  }
  // sum of squares of all M entries = qsq + lsq
  float part = 0.f;
  for (int e = l; e < D * D; e += 64) {
    float mv = M[e / D][e % D];
    part = fmaf(mv, mv, part);
  }
  red[l] = part;
  __syncthreads();
  for (int st = 32; st > 0; st >>= 1) {
    if (l < st) red[l] += red[l + st];
    __syncthreads();
  }
  if (l == 0) {
    float msq = red[0];
    float sumq = 0.f;
    for (int i = 0; i < D; ++i) sumq += ick[i];
    float bsq = 0.f;
    for (int i = 0; i < D; ++i) bsq = fmaf(b[i], b[i], bsq);
    eS = alphas[k] + sumq - 0.5f * bsq;
    float g = wg[0], mm = wm[0];
    wwk[k] = 0.5f * g * g * msq - mm * sumq;
  }
  __syncthreads();

  // write MFMA A-fragments: slice s = k>>4, row-in-slice = k&15
  int s = k >> 4, krow = k & 15;
  for (int u = l; u < NCHUNK * 4; u += 64) {
    int c = u >> 2, g = u & 3;
    unsigned int hw[4] = {0, 0, 0, 0}, lw[4] = {0, 0, 0, 0};
    for (int j2 = 0; j2 < 8; ++j2) {
      int f = c * 32 + g * 8 + j2;
      float wv;
      if (f == 0) wv = eS;
      else if (f <= 32) wv = v[f - 1];
      else if (f < 561) wv = At[f - 33];
      else wv = 0.0f;
      unsigned short hb = f2bf(wv);
      unsigned short lb = f2bf(wv - bf2f(hb));
      hw[j2 >> 1] |= ((unsigned int)hb) << (16 * (j2 & 1));
      lw[j2 >> 1] |= ((unsigned int)lb) << (16 * (j2 & 1));
    }
    int idx = (s * NCHUNK + c) * 64 + g * 16 + krow;
    Whi[idx] = make_uint4(hw[0], hw[1], hw[2], hw[3]);
    Wlo[idx] = make_uint4(lw[0], lw[1], lw[2], lw[3]);
  }
}

// ------------------- main: 32 points per block, 4 waves = 4 k-slices -------------------
__global__ __launch_bounds__(256) void gmm_main(
    const float* __restrict__ x, const int4* __restrict__ Whi,
    const int4* __restrict__ Wlo, int N, int Npad, float2* __restrict__ ms)
{
  __shared__ __align__(16) char phi[PTS_PER_BLK * ROWB];

  int tid = threadIdx.x;
  int lane = tid & 63;

  // ---- phase 1: feature generation (each thread: one point, 72 features) ----
  {
    int ptl = tid & 31;
    int h = tid >> 5;                 // 0..7
    int n = blockIdx.x * PTS_PER_BLK + ptl;
    int nn = (n < N) ? n : (N - 1);
    float xr[D];
    const float4* xp = reinterpret_cast<const float4*>(x + (size_t)nn * D);
#pragma unroll
    for (int i = 0; i < D / 4; ++i) {
      float4 vv = xp[i];
      xr[4 * i + 0] = vv.x; xr[4 * i + 1] = vv.y; xr[4 * i + 2] = vv.z; xr[4 * i + 3] = vv.w;
    }
    char* row = phi + (size_t)ptl * ROWB;
    switch (h) {
      case 0: gen72<  0>(xr, row, std::make_index_sequence<18>{}); break;
      case 1: gen72< 72>(xr, row, std::make_index_sequence<18>{}); break;
      case 2: gen72<144>(xr, row, std::make_index_sequence<18>{}); break;
      case 3: gen72<216>(xr, row, std::make_index_sequence<18>{}); break;
      case 4: gen72<288>(xr, row, std::make_index_sequence<18>{}); break;
      case 5: gen72<360>(xr, row, std::make_index_sequence<18>{}); break;
      case 6: gen72<432>(xr, row, std::make_index_sequence<18>{}); break;
      case 7: gen72<504>(xr, row, std::make_index_sequence<18>{}); break;
    }
  }
  __syncthreads();

  // ---- phase 2: GEMM inner[k, n] = W @ phi, one k-slice (16 k) per wave ----
  int slice = __builtin_amdgcn_readfirstlane(tid >> 6);
  int g = lane >> 4, n16 = lane & 15;

  v4f acc0 = {0.f, 0.f, 0.f, 0.f};
  v4f acc1 = {0.f, 0.f, 0.f, 0.f};
  const char* brow0 = phi + (size_t)(0 * 16 + n16) * ROWB + g * 16;
  const char* brow1 = phi + (size_t)(1 * 16 + n16) * ROWB + g * 16;

#pragma unroll
  for (int c = 0; c < NCHUNK; ++c) {
    int4 ah = Whi[(slice * NCHUNK + c) * 64 + lane];
    int4 al = Wlo[(slice * NCHUNK + c) * 64 + lane];
    int4 b0 = *reinterpret_cast<const int4*>(brow0 + c * 64);
    int4 b1 = *reinterpret_cast<const int4*>(brow1 + c * 64);
    v8s ahs = asv8(ah), als = asv8(al), b0s = asv8(b0), b1s = asv8(b1);
    acc0 = __builtin_amdgcn_mfma_f32_16x16x32_bf16(ahs, b0s, acc0, 0, 0, 0);
    acc0 = __builtin_amdgcn_mfma_f32_16x16x32_bf16(als, b0s, acc0, 0, 0, 0);
    acc1 = __builtin_amdgcn_mfma_f32_16x16x32_bf16(ahs, b1s, acc1, 0, 0, 0);
    acc1 = __builtin_amdgcn_mfma_f32_16x16x32_bf16(als, b1s, acc1, 0, 0, 0);
  }

  // ---- epilogue: per-lane lse over 4 k, merge across lane-groups (xor 16,32) ----
#pragma unroll
  for (int G = 0; G < 2; ++G) {
    v4f a = (G == 0) ? acc0 : acc1;
    float m = fmaxf(fmaxf(a.x, a.y), fmaxf(a.z, a.w));
    float sv = __expf(a.x - m) + __expf(a.y - m) + __expf(a.z - m) + __expf(a.w - m);
#pragma unroll
    for (int off = 16; off <= 32; off <<= 1) {
      float mo = __shfl_xor(m, off);
      float so = __shfl_xor(sv, off);
      float mn = fmaxf(m, mo);
      sv = sv * __expf(m - mn) + so * __expf(mo - mn);
      m = mn;
    }
    if (lane < 16)
      ms[(size_t)slice * Npad + blockIdx.x * PTS_PER_BLK + G * 16 + lane] = make_float2(m, sv);
  }
}

// ------------------- merge 4 k-slices per point + block reduce -------------------
__global__ __launch_bounds__(256) void gmm_merge(
    const float2* __restrict__ ms, int N, int Npad, float* __restrict__ partials)
{
  int tid = threadIdx.x;
  int idx = blockIdx.x * 256 + tid;
  int ii = (idx < N) ? idx : 0;

  float m[4], s[4];
#pragma unroll
  for (int kb = 0; kb < 4; ++kb) {
    float2 v = ms[(size_t)kb * Npad + ii];
    m[kb] = v.x; s[kb] = v.y;
  }
  float mm = fmaxf(fmaxf(m[0], m[1]), fmaxf(m[2], m[3]));
  float ss = 0.f;
#pragma unroll
  for (int kb = 0; kb < 4; ++kb) ss += s[kb] * __expf(m[kb] - mm);
  float lse = (idx < N) ? (mm + __logf(ss)) : 0.f;

  __shared__ float red[256];
  red[tid] = lse;
  __syncthreads();
#pragma unroll
  for (int st = 128; st > 0; st >>= 1) {
    if (tid < st) red[tid] += red[tid + st];
    __syncthreads();
  }
  if (tid == 0) partials[blockIdx.x] = red[0];
}

__global__ __launch_bounds__(256) void gmm_final(
    const float* __restrict__ wwk, const float* __restrict__ partials, int nblocks,
    const float* __restrict__ alphas, const float* __restrict__ wg,
    const float* __restrict__ wm, int N, float* __restrict__ out)
{
  int tid = threadIdx.x;
  __shared__ double sacc[256];
  double acc = 0.0;
  for (int i = tid; i < nblocks; i += 256) acc += (double)partials[i];
  sacc[tid] = acc;
  __syncthreads();
  for (int st = 128; st > 0; st >>= 1) {
    if (tid < st) sacc[tid] += sacc[tid + st];
    __syncthreads();
  }

  if (tid == 0) {
    double slse = sacc[0];

    float amax = alphas[0];
    for (int k = 1; k < K_COMP; ++k) amax = fmaxf(amax, alphas[k]);
    double sa = 0.0;
    for (int k = 0; k < K_COMP; ++k) sa += exp((double)(alphas[k] - amax));
    double lse_a = (double)amax + log(sa);

    double ow = 0.0;
    for (int k = 0; k < K_COMP; ++k) ow += (double)wwk[k];

    double g = (double)wg[0], wmv = (double)wm[0];
    double nw = (double)D + wmv + 1.0;
    double C = nw * (double)D * log(g / sqrt(2.0));
    double mg = (D * (D - 1) / 4.0) * log(M_PI);
    for (int j = 1; j <= D; ++j) mg += lgamma(0.5 * nw + (1.0 - j) * 0.5);

    double CONST = -(double)N * D * 0.5 * log(2.0 * M_PI);
    double prior = ow - (double)K_COMP * (C - mg);

    out[0] = (float)(CONST + slse - (double)N * lse_a + prior);
  }
}

extern "C" void kernel_launch(void* const* d_in, const int* in_sizes, int n_in,
                              void* d_out, int out_size, void* d_ws, size_t ws_size,
                              hipStream_t stream)
{
  const float* alphas = (const float*)d_in[0];
  const float* means  = (const float*)d_in[1];
  const float* icf    = (const float*)d_in[2];
  const float* x      = (const float*)d_in[3];
  const float* wg     = (const float*)d_in[4];
  const float* wm     = (const float*)d_in[5];
  float* out = (float*)d_out;

  int N = in_sizes[3] / D;
  int npblk = (N + PTS_PER_BLK - 1) / PTS_PER_BLK;   // 1563
  int Npad  = npblk * PTS_PER_BLK;                    // 50016
  int nmerge = (N + 255) / 256;                       // 196

  char* wsb = (char*)d_ws;
  const size_t WBYTES = (size_t)4 * NCHUNK * 64 * 16; // 73728 per array
  uint4*  Whi = (uint4*)wsb;
  uint4*  Wlo = (uint4*)(wsb + WBYTES);
  float*  wwk = (float*)(wsb + 2 * WBYTES);
  float2* ms  = (float2*)(wsb + 2 * WBYTES + 256);
  float*  partials = (float*)(ms + (size_t)4 * Npad);

  gmm_prep<<<K_COMP, 64, 0, stream>>>(alphas, means, icf, wg, wm, Whi, Wlo, wwk);
  gmm_main<<<npblk, 256, 0, stream>>>(x, (const int4*)Whi, (const int4*)Wlo, N, Npad, ms);
  gmm_merge<<<nmerge, 256, 0, stream>>>(ms, N, Npad, partials);
  gmm_final<<<1, 256, 0, stream>>>(wwk, partials, nmerge, alphas, wg, wm, N, out);
}

// Round 7
// 45.069 us; speedup vs baseline: 9.8379x; 1.4863x over previous
//
#include <hip/hip_runtime.h>
#include <math.h>
#include <utility>

#define K_COMP 64
#define D 32
#define NTRIL 496
#define ICF_COLS 528
#define NPAIR 528            // i<=j pairs
#define NF 561               // 1 + 32 + 528
#define NCHUNK 18            // 576 = 18*32 padded features
#define PTS_PER_BLK 32
#define ROWB 1168            // LDS feature-row stride in bytes (576*2 + 16)

typedef __attribute__((ext_vector_type(8))) short v8s;
typedef __attribute__((ext_vector_type(4))) float v4f;

__device__ __forceinline__ unsigned short f2bf(float f) {
  unsigned int u = __float_as_uint(f);
  unsigned int r = (u + 0x7FFFu + ((u >> 16) & 1u)) >> 16;
  return (unsigned short)r;
}
__device__ __forceinline__ float bf2f(unsigned short h) {
  return __uint_as_float((unsigned int)h << 16);
}
__device__ __forceinline__ v8s asv8(int4 v) {
  union { int4 i; v8s s; } u; u.i = v; return u.s;
}

// pair enumeration t -> (i,j), i<=j, i ascending, j from i..31
constexpr int pr_i(int t) { int i = 0; while (t >= D - i) { t -= D - i; ++i; } return i; }
constexpr int pr_j(int t) { int i = 0; while (t >= D - i) { t -= D - i; ++i; } return i + t; }

template<int F> __device__ __forceinline__ float feat(const float (&xr)[D]) {
  if constexpr (F == 0) return 1.0f;
  else if constexpr (F <= 32) return xr[F - 1];
  else if constexpr (F <= 560) {
    constexpr int t = F - 33, i = pr_i(t), j = pr_j(t);
    return xr[i] * xr[j];
  } else return 0.0f;
}

template<int F0> __device__ __forceinline__ void write4(const float (&xr)[D], char* row) {
  unsigned int d0 = (unsigned int)f2bf(feat<F0+0>(xr)) | ((unsigned int)f2bf(feat<F0+1>(xr)) << 16);
  unsigned int d1 = (unsigned int)f2bf(feat<F0+2>(xr)) | ((unsigned int)f2bf(feat<F0+3>(xr)) << 16);
  *reinterpret_cast<uint2*>(row + (size_t)F0 * 2) = make_uint2(d0, d1);
}
template<int BASE, size_t... Qs> __device__ __forceinline__
void gen72(const float (&xr)[D], char* row, std::index_sequence<Qs...>) {
  (write4<BASE + 4 * (int)Qs>(xr, row), ...);
}

// ------------------- prep: one block per component k -------------------
__global__ __launch_bounds__(64) void gmm_prep(
    const float* __restrict__ alphas, const float* __restrict__ means,
    const float* __restrict__ icf, const float* __restrict__ wg,
    const float* __restrict__ wm,
    uint4* __restrict__ Whi, uint4* __restrict__ Wlo, float* __restrict__ wwk)
{
  int k = blockIdx.x;
  int l = threadIdx.x;
  __shared__ float M[D][D + 1];
  __shared__ float mu[D], b[D], v[D];
  __shared__ float At[NPAIR];
  __shared__ float red[64];
  __shared__ float eS;

  const float* ick = icf + (size_t)k * ICF_COLS;

  if (l < D) {
    mu[l] = means[k * D + l];
    float q = __expf(ick[l]);
    for (int c = 0; c < D; ++c) {
      float val;
      if (c < l) { int off = c * 31 - c * (c - 1) / 2; val = ick[D + off + (l - c - 1)]; }
      else if (c == l) val = q;
      else val = 0.0f;
      M[l][c] = val;
    }
  }
  __syncthreads();
  if (l < D) {
    float acc = 0.f;
    for (int c = 0; c < D; ++c) acc = fmaf(M[l][c], mu[c], acc);
    b[l] = acc;
  }
  __syncthreads();
  if (l < D) {
    float acc = 0.f;
    for (int r = 0; r < D; ++r) acc = fmaf(M[r][l], b[r], acc);
    v[l] = acc;
  }
  // A[i<=j] = sum_r M[r,i]*M[r,j]; store with GEMM sign convention
  for (int t = l; t < NPAIR; t += 64) {
    int tt = t, i = 0;
    while (tt >= D - i) { tt -= D - i; ++i; }
    int j = i + tt;
    float acc = 0.f;
    for (int r = 0; r < D; ++r) acc = fmaf(M[r][i], M[r][j], acc);
    At[t] = (i == j) ? -0.5f * acc : -acc;
  }
  // sum of squares of all M entries = qsq + lsq
  float part = 0.f;
  for (int e = l; e < D * D; e += 64) {
    float mv = M[e / D][e % D];
    part = fmaf(mv, mv, part);
  }
  red[l] = part;
  __syncthreads();
  for (int st = 32; st > 0; st >>= 1) {
    if (l < st) red[l] += red[l + st];
    __syncthreads();
  }
  if (l == 0) {
    float msq = red[0];
    float sumq = 0.f;
    for (int i = 0; i < D; ++i) sumq += ick[i];
    float bsq = 0.f;
    for (int i = 0; i < D; ++i) bsq = fmaf(b[i], b[i], bsq);
    eS = alphas[k] + sumq - 0.5f * bsq;
    float g = wg[0], mm = wm[0];
    wwk[k] = 0.5f * g * g * msq - mm * sumq;
  }
  __syncthreads();

  // write MFMA A-fragments: slice s = k>>4, row-in-slice = k&15
  int s = k >> 4, krow = k & 15;
  for (int u = l; u < NCHUNK * 4; u += 64) {
    int c = u >> 2, g = u & 3;
    unsigned int hw[4] = {0, 0, 0, 0}, lw[4] = {0, 0, 0, 0};
    for (int j2 = 0; j2 < 8; ++j2) {
      int f = c * 32 + g * 8 + j2;
      float wv;
      if (f == 0) wv = eS;
      else if (f <= 32) wv = v[f - 1];
      else if (f < 561) wv = At[f - 33];
      else wv = 0.0f;
      unsigned short hb = f2bf(wv);
      unsigned short lb = f2bf(wv - bf2f(hb));
      hw[j2 >> 1] |= ((unsigned int)hb) << (16 * (j2 & 1));
      lw[j2 >> 1] |= ((unsigned int)lb) << (16 * (j2 & 1));
    }
    int idx = (s * NCHUNK + c) * 64 + g * 16 + krow;
    Whi[idx] = make_uint4(hw[0], hw[1], hw[2], hw[3]);
    Wlo[idx] = make_uint4(lw[0], lw[1], lw[2], lw[3]);
  }
}

// ------------------- main: 32 points per block, 4 waves = 4 k-slices -------------------
__global__ __launch_bounds__(256) void gmm_main(
    const float* __restrict__ x, const int4* __restrict__ Whi,
    const int4* __restrict__ Wlo, int N, float* __restrict__ partials)
{
  __shared__ __align__(16) char phi[PTS_PER_BLK * ROWB];
  __shared__ float lmm[4][PTS_PER_BLK];
  __shared__ float lss[4][PTS_PER_BLK];

  int tid = threadIdx.x;
  int lane = tid & 63;

  // ---- phase 1: feature generation (each thread: one point, 72 features) ----
  {
    int ptl = tid & 31;
    int h = tid >> 5;                 // 0..7
    int n = blockIdx.x * PTS_PER_BLK + ptl;
    int nn = (n < N) ? n : (N - 1);
    float xr[D];
    const float4* xp = reinterpret_cast<const float4*>(x + (size_t)nn * D);
#pragma unroll
    for (int i = 0; i < D / 4; ++i) {
      float4 vv = xp[i];
      xr[4 * i + 0] = vv.x; xr[4 * i + 1] = vv.y; xr[4 * i + 2] = vv.z; xr[4 * i + 3] = vv.w;
    }
    char* row = phi + (size_t)ptl * ROWB;
    switch (h) {
      case 0: gen72<  0>(xr, row, std::make_index_sequence<18>{}); break;
      case 1: gen72< 72>(xr, row, std::make_index_sequence<18>{}); break;
      case 2: gen72<144>(xr, row, std::make_index_sequence<18>{}); break;
      case 3: gen72<216>(xr, row, std::make_index_sequence<18>{}); break;
      case 4: gen72<288>(xr, row, std::make_index_sequence<18>{}); break;
      case 5: gen72<360>(xr, row, std::make_index_sequence<18>{}); break;
      case 6: gen72<432>(xr, row, std::make_index_sequence<18>{}); break;
      case 7: gen72<504>(xr, row, std::make_index_sequence<18>{}); break;
    }
  }
  __syncthreads();

  // ---- phase 2: GEMM inner[k, n] = W @ phi, one k-slice (16 k) per wave ----
  int slice = __builtin_amdgcn_readfirstlane(tid >> 6);
  int g = lane >> 4, n16 = lane & 15;

  v4f acc0 = {0.f, 0.f, 0.f, 0.f};
  v4f acc1 = {0.f, 0.f, 0.f, 0.f};
  const char* brow0 = phi + (size_t)(0 * 16 + n16) * ROWB + g * 16;
  const char* brow1 = phi + (size_t)(1 * 16 + n16) * ROWB + g * 16;

#pragma unroll
  for (int c = 0; c < NCHUNK; ++c) {
    int4 ah = Whi[(slice * NCHUNK + c) * 64 + lane];
    int4 al = Wlo[(slice * NCHUNK + c) * 64 + lane];
    int4 b0 = *reinterpret_cast<const int4*>(brow0 + c * 64);
    int4 b1 = *reinterpret_cast<const int4*>(brow1 + c * 64);
    v8s ahs = asv8(ah), als = asv8(al), b0s = asv8(b0), b1s = asv8(b1);
    acc0 = __builtin_amdgcn_mfma_f32_16x16x32_bf16(ahs, b0s, acc0, 0, 0, 0);
    acc0 = __builtin_amdgcn_mfma_f32_16x16x32_bf16(als, b0s, acc0, 0, 0, 0);
    acc1 = __builtin_amdgcn_mfma_f32_16x16x32_bf16(ahs, b1s, acc1, 0, 0, 0);
    acc1 = __builtin_amdgcn_mfma_f32_16x16x32_bf16(als, b1s, acc1, 0, 0, 0);
  }

  // ---- epilogue: per-lane lse over 4 k, merge lane-groups, stash per-slice in LDS ----
#pragma unroll
  for (int G = 0; G < 2; ++G) {
    v4f a = (G == 0) ? acc0 : acc1;
    float m = fmaxf(fmaxf(a.x, a.y), fmaxf(a.z, a.w));
    float sv = __expf(a.x - m) + __expf(a.y - m) + __expf(a.z - m) + __expf(a.w - m);
#pragma unroll
    for (int off = 16; off <= 32; off <<= 1) {
      float mo = __shfl_xor(m, off);
      float so = __shfl_xor(sv, off);
      float mn = fmaxf(m, mo);
      sv = sv * __expf(m - mn) + so * __expf(mo - mn);
      m = mn;
    }
    if (lane < 16) { lmm[slice][G * 16 + lane] = m; lss[slice][G * 16 + lane] = sv; }
  }
  __syncthreads();

  // ---- in-block merge of the 4 k-slices + block reduction -> 1 float ----
  if (tid < PTS_PER_BLK) {
    float m0 = lmm[0][tid], m1 = lmm[1][tid], m2 = lmm[2][tid], m3 = lmm[3][tid];
    float mm = fmaxf(fmaxf(m0, m1), fmaxf(m2, m3));
    float ss = lss[0][tid] * __expf(m0 - mm) + lss[1][tid] * __expf(m1 - mm)
             + lss[2][tid] * __expf(m2 - mm) + lss[3][tid] * __expf(m3 - mm);
    int n = blockIdx.x * PTS_PER_BLK + tid;
    float lse = (n < N) ? (mm + __logf(ss)) : 0.f;
#pragma unroll
    for (int off = 16; off > 0; off >>= 1) lse += __shfl_down(lse, off);
    if (tid == 0) partials[blockIdx.x] = lse;
  }
}

// ------------------- final: parallel reductions + parallel special functions -------------------
__global__ __launch_bounds__(256) void gmm_final(
    const float* __restrict__ wwk, const float* __restrict__ partials, int nblocks,
    const float* __restrict__ alphas, const float* __restrict__ wg,
    const float* __restrict__ wm, int N, float* __restrict__ out)
{
  int tid = threadIdx.x;
  __shared__ double sd[256];
  __shared__ float samax;
  __shared__ double s_slse, s_sa, s_ow, s_mgsum;

  // 1) sum of per-block lse partials (double, deterministic tree)
  double acc = 0.0;
  for (int i = tid; i < nblocks; i += 256) acc += (double)partials[i];
  sd[tid] = acc;
  __syncthreads();
  for (int st = 128; st > 0; st >>= 1) {
    if (tid < st) sd[tid] += sd[tid + st];
    __syncthreads();
  }
  if (tid == 0) s_slse = sd[0];
  __syncthreads();

  // 2) max(alphas) via wave 0 shuffle
  if (tid < 64) {
    float m = alphas[tid];
#pragma unroll
    for (int off = 32; off > 0; off >>= 1) m = fmaxf(m, __shfl_xor(m, off));
    if (tid == 0) samax = m;
  }
  __syncthreads();

  // 3) sum exp(alphas - amax) in double, parallel
  sd[tid] = (tid < K_COMP) ? exp((double)(alphas[tid] - samax)) : 0.0;
  __syncthreads();
  for (int st = 128; st > 0; st >>= 1) {
    if (tid < st) sd[tid] += sd[tid + st];
    __syncthreads();
  }
  if (tid == 0) s_sa = sd[0];
  __syncthreads();

  // 4) sum wwk (wishart data part), parallel
  sd[tid] = (tid < K_COMP) ? (double)wwk[tid] : 0.0;
  __syncthreads();
  for (int st = 128; st > 0; st >>= 1) {
    if (tid < st) sd[tid] += sd[tid + st];
    __syncthreads();
  }
  if (tid == 0) s_ow = sd[0];
  __syncthreads();

  // 5) multigammaln lgamma terms, one per thread j=tid+1 (32 threads)
  double nw = (double)D + (double)wm[0] + 1.0;
  sd[tid] = (tid < D) ? lgamma(0.5 * nw + (1.0 - (double)(tid + 1)) * 0.5) : 0.0;
  __syncthreads();
  for (int st = 128; st > 0; st >>= 1) {
    if (tid < st) sd[tid] += sd[tid + st];
    __syncthreads();
  }

  if (tid == 0) {
    double mg = (D * (D - 1) / 4.0) * log(M_PI) + sd[0];
    double lse_a = (double)samax + log(s_sa);
    double g = (double)wg[0];
    double C = nw * (double)D * log(g / sqrt(2.0));
    double CONST = -(double)N * D * 0.5 * log(2.0 * M_PI);
    double prior = s_ow - (double)K_COMP * (C - mg);
    out[0] = (float)(CONST + s_slse - (double)N * lse_a + prior);
  }
}

extern "C" void kernel_launch(void* const* d_in, const int* in_sizes, int n_in,
                              void* d_out, int out_size, void* d_ws, size_t ws_size,
                              hipStream_t stream)
{
  const float* alphas = (const float*)d_in[0];
  const float* means  = (const float*)d_in[1];
  const float* icf    = (const float*)d_in[2];
  const float* x      = (const float*)d_in[3];
  const float* wg     = (const float*)d_in[4];
  const float* wm     = (const float*)d_in[5];
  float* out = (float*)d_out;

  int N = in_sizes[3] / D;
  int npblk = (N + PTS_PER_BLK - 1) / PTS_PER_BLK;   // 1563

  char* wsb = (char*)d_ws;
  const size_t WBYTES = (size_t)4 * NCHUNK * 64 * 16; // 73728 per array
  uint4*  Whi = (uint4*)wsb;
  uint4*  Wlo = (uint4*)(wsb + WBYTES);
  float*  wwk = (float*)(wsb + 2 * WBYTES);
  float*  partials = (float*)(wsb + 2 * WBYTES + 256);

  gmm_prep<<<K_COMP, 64, 0, stream>>>(alphas, means, icf, wg, wm, Whi, Wlo, wwk);
  gmm_main<<<npblk, 256, 0, stream>>>(x, (const int4*)Whi, (const int4*)Wlo, N, partials);
  gmm_final<<<1, 256, 0, stream>>>(wwk, partials, npblk, alphas, wg, wm, N, out);
}

// Round 8
// 42.288 us; speedup vs baseline: 10.4850x; 1.0658x over previous
//
#include <hip/hip_runtime.h>
#include <math.h>
#include <utility>

#define K_COMP 64
#define D 32
#define NTRIL 496
#define ICF_COLS 528
#define NPAIR 528            // i<=j pairs
#define NFEAT 560            // 32 linear + 528 pair (constant term moved to epilogue)
#define NCHUNK 18            // 576 = 18*32 padded features
#define PTS_PER_BLK 32
#define ROWB 1168            // LDS feature-row stride in bytes (576*2 + 16)

typedef __attribute__((ext_vector_type(8))) short v8s;
typedef __attribute__((ext_vector_type(4))) float v4f;

__device__ __forceinline__ unsigned short f2bf(float f) {
  unsigned int u = __float_as_uint(f);
  unsigned int r = (u + 0x7FFFu + ((u >> 16) & 1u)) >> 16;
  return (unsigned short)r;
}
__device__ __forceinline__ v8s asv8(int4 v) {
  union { int4 i; v8s s; } u; u.i = v; return u.s;
}

// pair enumeration t -> (i,j), i<=j, i ascending, j from i..31
constexpr int pr_i(int t) { int i = 0; while (t >= D - i) { t -= D - i; ++i; } return i; }
constexpr int pr_j(int t) { int i = 0; while (t >= D - i) { t -= D - i; ++i; } return i + t; }

// feature f: [0,32) = x[f]; [32,560) = x_i*x_j; [560,576) = 0 pad
template<int F> __device__ __forceinline__ float feat(const float (&xr)[D]) {
  if constexpr (F < 32) return xr[F];
  else if constexpr (F < NFEAT) {
    constexpr int t = F - 32, i = pr_i(t), j = pr_j(t);
    return xr[i] * xr[j];
  } else return 0.0f;
}

template<int F0> __device__ __forceinline__ void write4(const float (&xr)[D], char* row) {
  unsigned int d0 = (unsigned int)f2bf(feat<F0+0>(xr)) | ((unsigned int)f2bf(feat<F0+1>(xr)) << 16);
  unsigned int d1 = (unsigned int)f2bf(feat<F0+2>(xr)) | ((unsigned int)f2bf(feat<F0+3>(xr)) << 16);
  *reinterpret_cast<uint2*>(row + (size_t)F0 * 2) = make_uint2(d0, d1);
}
template<int BASE, size_t... Qs> __device__ __forceinline__
void gen72(const float (&xr)[D], char* row, std::index_sequence<Qs...>) {
  (write4<BASE + 4 * (int)Qs>(xr, row), ...);
}

// ------------------- prep: one block per component k -------------------
__global__ __launch_bounds__(64) void gmm_prep(
    const float* __restrict__ alphas, const float* __restrict__ means,
    const float* __restrict__ icf, const float* __restrict__ wg,
    const float* __restrict__ wm,
    uint4* __restrict__ Whi, float* __restrict__ eSa, float* __restrict__ wwk)
{
  int k = blockIdx.x;
  int l = threadIdx.x;
  __shared__ float M[D][D + 1];
  __shared__ float mu[D], b[D], v[D];
  __shared__ float At[NPAIR];
  __shared__ float red[64];

  const float* ick = icf + (size_t)k * ICF_COLS;

  if (l < D) {
    mu[l] = means[k * D + l];
    float q = __expf(ick[l]);
    for (int c = 0; c < D; ++c) {
      float val;
      if (c < l) { int off = c * 31 - c * (c - 1) / 2; val = ick[D + off + (l - c - 1)]; }
      else if (c == l) val = q;
      else val = 0.0f;
      M[l][c] = val;
    }
  }
  __syncthreads();
  if (l < D) {
    float acc = 0.f;
    for (int c = 0; c < D; ++c) acc = fmaf(M[l][c], mu[c], acc);
    b[l] = acc;
  }
  __syncthreads();
  if (l < D) {
    float acc = 0.f;
    for (int r = 0; r < D; ++r) acc = fmaf(M[r][l], b[r], acc);
    v[l] = acc;
  }
  // A[i<=j] = sum_r M[r,i]*M[r,j]; GEMM sign convention (-1/2 diag, -1 off)
  for (int t = l; t < NPAIR; t += 64) {
    int tt = t, i = 0;
    while (tt >= D - i) { tt -= D - i; ++i; }
    int j = i + tt;
    float acc = 0.f;
    for (int r = 0; r < D; ++r) acc = fmaf(M[r][i], M[r][j], acc);
    At[t] = (i == j) ? -0.5f * acc : -acc;
  }
  // sum of squares of all M entries = qsq + lsq
  float part = 0.f;
  for (int e = l; e < D * D; e += 64) {
    float mv = M[e / D][e % D];
    part = fmaf(mv, mv, part);
  }
  red[l] = part;
  __syncthreads();
  for (int st = 32; st > 0; st >>= 1) {
    if (l < st) red[l] += red[l + st];
    __syncthreads();
  }
  if (l == 0) {
    float msq = red[0];
    float sumq = 0.f;
    for (int i = 0; i < D; ++i) sumq += ick[i];
    float bsq = 0.f;
    for (int i = 0; i < D; ++i) bsq = fmaf(b[i], b[i], bsq);
    eSa[k] = alphas[k] + sumq - 0.5f * bsq;   // f32 epilogue constant
    float g = wg[0], mm = wm[0];
    wwk[k] = 0.5f * g * g * msq - mm * sumq;
  }
  __syncthreads();

  // write MFMA A-fragments (hi only): slice s = k>>4, row-in-slice = k&15
  int s = k >> 4, krow = k & 15;
  for (int u = l; u < NCHUNK * 4; u += 64) {
    int c = u >> 2, g = u & 3;
    unsigned int hw[4] = {0, 0, 0, 0};
    for (int j2 = 0; j2 < 8; ++j2) {
      int f = c * 32 + g * 8 + j2;
      float wv2;
      if (f < 32) wv2 = v[f];
      else if (f < NFEAT) wv2 = At[f - 32];
      else wv2 = 0.0f;
      hw[j2 >> 1] |= ((unsigned int)f2bf(wv2)) << (16 * (j2 & 1));
    }
    Whi[(s * NCHUNK + c) * 64 + g * 16 + krow] = make_uint4(hw[0], hw[1], hw[2], hw[3]);
  }
}

// ------------------- main: 32 points per block, 4 waves = 4 k-slices -------------------
__global__ __launch_bounds__(256) void gmm_main(
    const float* __restrict__ x, const int4* __restrict__ Whi,
    const float* __restrict__ eSa, int N, float* __restrict__ partials)
{
  __shared__ __align__(16) char phi[PTS_PER_BLK * ROWB];
  __shared__ float lmm[4][PTS_PER_BLK];
  __shared__ float lss[4][PTS_PER_BLK];

  int tid = threadIdx.x;
  int lane = tid & 63;

  // ---- phase 1: feature generation (each thread: one point, 72 features) ----
  {
    int ptl = tid & 31;
    int h = tid >> 5;                 // 0..7
    int n = blockIdx.x * PTS_PER_BLK + ptl;
    int nn = (n < N) ? n : (N - 1);
    float xr[D];
    const float4* xp = reinterpret_cast<const float4*>(x + (size_t)nn * D);
#pragma unroll
    for (int i = 0; i < D / 4; ++i) {
      float4 vv = xp[i];
      xr[4 * i + 0] = vv.x; xr[4 * i + 1] = vv.y; xr[4 * i + 2] = vv.z; xr[4 * i + 3] = vv.w;
    }
    char* row = phi + (size_t)ptl * ROWB;
    switch (h) {
      case 0: gen72<  0>(xr, row, std::make_index_sequence<18>{}); break;
      case 1: gen72< 72>(xr, row, std::make_index_sequence<18>{}); break;
      case 2: gen72<144>(xr, row, std::make_index_sequence<18>{}); break;
      case 3: gen72<216>(xr, row, std::make_index_sequence<18>{}); break;
      case 4: gen72<288>(xr, row, std::make_index_sequence<18>{}); break;
      case 5: gen72<360>(xr, row, std::make_index_sequence<18>{}); break;
      case 6: gen72<432>(xr, row, std::make_index_sequence<18>{}); break;
      case 7: gen72<504>(xr, row, std::make_index_sequence<18>{}); break;
    }
  }
  __syncthreads();

  // ---- phase 2: GEMM inner[k, n] = W @ phi, one k-slice (16 k) per wave ----
  int slice = __builtin_amdgcn_readfirstlane(tid >> 6);
  int g = lane >> 4, n16 = lane & 15;

  v4f acc0 = {0.f, 0.f, 0.f, 0.f};
  v4f acc1 = {0.f, 0.f, 0.f, 0.f};
  const char* brow0 = phi + (size_t)(0 * 16 + n16) * ROWB + g * 16;
  const char* brow1 = phi + (size_t)(1 * 16 + n16) * ROWB + g * 16;

#pragma unroll
  for (int c = 0; c < NCHUNK; ++c) {
    int4 ah = Whi[(slice * NCHUNK + c) * 64 + lane];
    int4 b0 = *reinterpret_cast<const int4*>(brow0 + c * 64);
    int4 b1 = *reinterpret_cast<const int4*>(brow1 + c * 64);
    v8s ahs = asv8(ah), b0s = asv8(b0), b1s = asv8(b1);
    acc0 = __builtin_amdgcn_mfma_f32_16x16x32_bf16(ahs, b0s, acc0, 0, 0, 0);
    acc1 = __builtin_amdgcn_mfma_f32_16x16x32_bf16(ahs, b1s, acc1, 0, 0, 0);
  }

  // ---- epilogue: add f32 constant eS[k], per-lane lse over 4 k, merge lane-groups ----
  float4 es = reinterpret_cast<const float4*>(eSa)[slice * 4 + (lane >> 4)];
  acc0.x += es.x; acc0.y += es.y; acc0.z += es.z; acc0.w += es.w;
  acc1.x += es.x; acc1.y += es.y; acc1.z += es.z; acc1.w += es.w;

#pragma unroll
  for (int G = 0; G < 2; ++G) {
    v4f a = (G == 0) ? acc0 : acc1;
    float m = fmaxf(fmaxf(a.x, a.y), fmaxf(a.z, a.w));
    float sv = __expf(a.x - m) + __expf(a.y - m) + __expf(a.z - m) + __expf(a.w - m);
#pragma unroll
    for (int off = 16; off <= 32; off <<= 1) {
      float mo = __shfl_xor(m, off);
      float so = __shfl_xor(sv, off);
      float mn = fmaxf(m, mo);
      sv = sv * __expf(m - mn) + so * __expf(mo - mn);
      m = mn;
    }
    if (lane < 16) { lmm[slice][G * 16 + lane] = m; lss[slice][G * 16 + lane] = sv; }
  }
  __syncthreads();

  // ---- in-block merge of the 4 k-slices + block reduction -> 1 float ----
  if (tid < PTS_PER_BLK) {
    float m0 = lmm[0][tid], m1 = lmm[1][tid], m2 = lmm[2][tid], m3 = lmm[3][tid];
    float mm = fmaxf(fmaxf(m0, m1), fmaxf(m2, m3));
    float ss = lss[0][tid] * __expf(m0 - mm) + lss[1][tid] * __expf(m1 - mm)
             + lss[2][tid] * __expf(m2 - mm) + lss[3][tid] * __expf(m3 - mm);
    int n = blockIdx.x * PTS_PER_BLK + tid;
    float lse = (n < N) ? (mm + __logf(ss)) : 0.f;
#pragma unroll
    for (int off = 16; off > 0; off >>= 1) lse += __shfl_down(lse, off);
    if (tid == 0) partials[blockIdx.x] = lse;
  }
}

// ------------------- final: parallel reductions + parallel special functions -------------------
__global__ __launch_bounds__(256) void gmm_final(
    const float* __restrict__ wwk, const float* __restrict__ partials, int nblocks,
    const float* __restrict__ alphas, const float* __restrict__ wg,
    const float* __restrict__ wm, int N, float* __restrict__ out)
{
  int tid = threadIdx.x;
  __shared__ double sd[256];
  __shared__ float samax;
  __shared__ double s_slse, s_sa, s_ow;

  // 1) sum of per-block lse partials (double, deterministic tree)
  double acc = 0.0;
  for (int i = tid; i < nblocks; i += 256) acc += (double)partials[i];
  sd[tid] = acc;
  __syncthreads();
  for (int st = 128; st > 0; st >>= 1) {
    if (tid < st) sd[tid] += sd[tid + st];
    __syncthreads();
  }
  if (tid == 0) s_slse = sd[0];
  __syncthreads();

  // 2) max(alphas) via wave 0 shuffle
  if (tid < 64) {
    float m = alphas[tid];
#pragma unroll
    for (int off = 32; off > 0; off >>= 1) m = fmaxf(m, __shfl_xor(m, off));
    if (tid == 0) samax = m;
  }
  __syncthreads();

  // 3) sum exp(alphas - amax) in double, parallel
  sd[tid] = (tid < K_COMP) ? exp((double)(alphas[tid] - samax)) : 0.0;
  __syncthreads();
  for (int st = 128; st > 0; st >>= 1) {
    if (tid < st) sd[tid] += sd[tid + st];
    __syncthreads();
  }
  if (tid == 0) s_sa = sd[0];
  __syncthreads();

  // 4) sum wwk (wishart data part), parallel
  sd[tid] = (tid < K_COMP) ? (double)wwk[tid] : 0.0;
  __syncthreads();
  for (int st = 128; st > 0; st >>= 1) {
    if (tid < st) sd[tid] += sd[tid + st];
    __syncthreads();
  }
  if (tid == 0) s_ow = sd[0];
  __syncthreads();

  // 5) multigammaln lgamma terms, one per thread j=tid+1 (32 threads)
  double nw = (double)D + (double)wm[0] + 1.0;
  sd[tid] = (tid < D) ? lgamma(0.5 * nw + (1.0 - (double)(tid + 1)) * 0.5) : 0.0;
  __syncthreads();
  for (int st = 128; st > 0; st >>= 1) {
    if (tid < st) sd[tid] += sd[tid + st];
    __syncthreads();
  }

  if (tid == 0) {
    double mg = (D * (D - 1) / 4.0) * log(M_PI) + sd[0];
    double lse_a = (double)samax + log(s_sa);
    double g = (double)wg[0];
    double C = nw * (double)D * log(g / sqrt(2.0));
    double CONST = -(double)N * D * 0.5 * log(2.0 * M_PI);
    double prior = s_ow - (double)K_COMP * (C - mg);
    out[0] = (float)(CONST + s_slse - (double)N * lse_a + prior);
  }
}

extern "C" void kernel_launch(void* const* d_in, const int* in_sizes, int n_in,
                              void* d_out, int out_size, void* d_ws, size_t ws_size,
                              hipStream_t stream)
{
  const float* alphas = (const float*)d_in[0];
  const float* means  = (const float*)d_in[1];
  const float* icf    = (const float*)d_in[2];
  const float* x      = (const float*)d_in[3];
  const float* wg     = (const float*)d_in[4];
  const float* wm     = (const float*)d_in[5];
  float* out = (float*)d_out;

  int N = in_sizes[3] / D;
  int npblk = (N + PTS_PER_BLK - 1) / PTS_PER_BLK;   // 1563

  char* wsb = (char*)d_ws;
  const size_t WBYTES = (size_t)4 * NCHUNK * 64 * 16; // 73728
  uint4* Whi = (uint4*)wsb;
  float* eSa = (float*)(wsb + WBYTES);
  float* wwk = eSa + K_COMP;
  float* partials = wwk + K_COMP;

  gmm_prep<<<K_COMP, 64, 0, stream>>>(alphas, means, icf, wg, wm, Whi, eSa, wwk);
  gmm_main<<<npblk, 256, 0, stream>>>(x, (const int4*)Whi, eSa, N, partials);
  gmm_final<<<1, 256, 0, stream>>>(wwk, partials, npblk, alphas, wg, wm, N, out);
}